// Round 2
// baseline (175.247 us; speedup 1.0000x reference)
//
#include <hip/hip_runtime.h>

#define B_ 8
#define H_ 512
#define W_ 1024

// ---------------- Stage 1 geometry ----------------
#define TILE 32
#define HD 4                 // evolving-image halo (r_max=3 + 1 conv)
#define RD 40                // TILE + 2*HD
#define HB 7                 // boundary halo = HD + 3 (dist cap)
#define RB 46                // TILE + 2*HB
#define HP 8                 // pred halo = HB + 1
#define RP 48                // TILE + 2*HP

__device__ __forceinline__ int clampi(int v, int lo, int hi) {
    return v < lo ? lo : (v > hi ? hi : v);
}
__device__ __forceinline__ int imax(int a, int b) { return a > b ? a : b; }
__device__ __forceinline__ int imin(int a, int b) { return a < b ? a : b; }

// boundaries + dist-via-bitmap-dilation + 4 separable masked-average iterations
__global__ __launch_bounds__(256)
void bsws_stage1(const float* __restrict__ xg, const int* __restrict__ predg,
                 float* __restrict__ outg)
{
    __shared__ int sPred[RP * RP];                    // 9.2 KB
    __shared__ unsigned long long sB[4][RB];          // b0..b3 row bitmaps, 1.5 KB
    __shared__ float sA[RD * RD];                     // ping
    __shared__ float sC[RD * RD];                     // pong
    __shared__ float sHX[RD * RD];                    // horizontal sum of masked x
    __shared__ float sHM[RD * RD];                    // horizontal sum of mask

    const int tid = threadIdx.x;
    const int x0 = blockIdx.x * TILE;
    const int y0 = blockIdx.y * TILE;
    const size_t plane = (size_t)H_ * W_;
    const int*   pp = predg + blockIdx.z * plane;
    const float* xp = xg    + blockIdx.z * plane;
    float*       op = outg  + blockIdx.z * plane;

    const bool leftB  = (x0 == 0), rightB = (x0 + TILE == W_);
    const bool topB   = (y0 == 0), botB   = (y0 + TILE == H_);
    const bool borderB = leftB || rightB || topB || botB;

    // ---- load pred (sentinel -1 OOB) and x (edge-clamped) ----
    for (int i = tid; i < RP * RP; i += 256) {
        int ry = i / RP, rx = i - ry * RP;
        int gy = y0 - HP + ry, gx = x0 - HP + rx;
        sPred[i] = (gy >= 0 && gy < H_ && gx >= 0 && gx < W_) ? pp[(size_t)gy * W_ + gx] : -1;
    }
    for (int i = tid; i < RD * RD; i += 256) {
        int ry = i / RD, rx = i - ry * RD;
        int gy = clampi(y0 - HD + ry, 0, H_ - 1);
        int gx = clampi(x0 - HD + rx, 0, W_ - 1);
        sA[i] = xp[(size_t)gy * W_ + gx];
    }
    __syncthreads();

    // ---- b0: boundary bitmap via ballot (lane = column) ----
    {
        const int lane = tid & 63, wv = tid >> 6;
        for (int row = wv; row < RB; row += 4) {
            bool pred = false;
            if (lane < RB) {
                const int py = row + 1, px = lane + 1;     // 48-frame
                int c = sPred[py * RP + px];
                if (c >= 0) {
                    int up = sPred[(py - 1) * RP + px];
                    int dn = sPred[(py + 1) * RP + px];
                    int lf = sPred[py * RP + px - 1];
                    int rt = sPred[py * RP + px + 1];
                    int ul = sPred[(py - 1) * RP + px - 1];
                    int ur = sPred[(py - 1) * RP + px + 1];
                    int dl = sPred[(py + 1) * RP + px - 1];
                    int dr = sPred[(py + 1) * RP + px + 1];
                    // max over cross (OOB=-1 never wins); min over 8 nbrs (OOB->+inf)
                    int mx = imax(imax(up, dn), imax(lf, rt));
                    int B = 0x7fffffff;
                    int mn = imin(imin(imin(up < 0 ? B : up, dn < 0 ? B : dn),
                                       imin(lf < 0 ? B : lf, rt < 0 ? B : rt)),
                                  imin(imin(ul < 0 ? B : ul, ur < 0 ? B : ur),
                                       imin(dl < 0 ? B : dl, dr < 0 ? B : dr)));
                    pred = (mx > c) || (mn < c);
                }
            }
            unsigned long long bal = __ballot(pred);
            if (lane == 0) sB[0][row] = bal;
        }
    }
    __syncthreads();

    // ---- cross-dilations b1..b3 (full-plane == in-image for rectangles) ----
    #pragma unroll
    for (int lvl = 1; lvl < 4; ++lvl) {
        if (tid < RB) {
            unsigned long long c = sB[lvl - 1][tid];
            unsigned long long u = (tid > 0)      ? sB[lvl - 1][tid - 1] : 0ULL;
            unsigned long long d = (tid < RB - 1) ? sB[lvl - 1][tid + 1] : 0ULL;
            sB[lvl][tid] = c | (c << 1) | (c >> 1) | u | d;
        }
        __syncthreads();
    }

    // ---- border blocks: edge-replicate bitmap halo (mask uses edge padding) ----
    if (borderB) {
        const bool act = tid < 4 * RB;
        unsigned long long val = 0; int lvl = 0, row = 0;
        if (act) {
            lvl = tid / RB; row = tid - lvl * RB;
            int srcRow = clampi(row, topB ? HB : 0, botB ? (RB - 1 - HB) : RB - 1);
            val = sB[lvl][srcRow];
            if (leftB) {
                unsigned long long b = (val >> HB) & 1ULL;
                unsigned long long lo = (1ULL << HB) - 1;              // bits 0..6
                val = (val & ~lo) | (b ? lo : 0ULL);
            }
            if (rightB) {
                const int jb = RB - 1 - HB;                             // 38 == gx=W-1
                unsigned long long b = (val >> jb) & 1ULL;
                unsigned long long keep = (1ULL << (jb + 1)) - 1;
                unsigned long long hi = (((1ULL << RB) - 1) & ~keep);  // bits 39..45
                val = (val & keep) | (b ? hi : 0ULL);
            }
        }
        __syncthreads();
        if (act) sB[lvl][row] = val;
    }
    __syncthreads();

    // ---- 4 masked-average iterations, separable 3x3 sums ----
    float* cur = sA;
    float* nxt = sC;
    #pragma unroll
    for (int it = 0; it < 4; ++it) {
        const int r = 3 - it;
        const unsigned long long* br = sB[r];

        // pass A: horizontal sums over full RD x RD (edges produce unread garbage)
        for (int i = tid; i < RD * RD; i += 256) {
            int ry = i / RD, rx = i - ry * RD;
            unsigned long long row = br[ry + (HB - HD)];
            int rxm = rx > 0 ? rx - 1 : 0;
            int rxp = rx < RD - 1 ? rx + 1 : RD - 1;
            float m0 = ((row >> (rx + 2)) & 1ULL) ? 0.f : 1.f;   // col rx-1
            float m1 = ((row >> (rx + 3)) & 1ULL) ? 0.f : 1.f;   // col rx
            float m2 = ((row >> (rx + 4)) & 1ULL) ? 0.f : 1.f;   // col rx+1
            float a0 = cur[ry * RD + rxm];
            float a1 = cur[ry * RD + rx];
            float a2 = cur[ry * RD + rxp];
            sHX[i] = m0 * a0 + m1 * a1 + m2 * a2;
            sHM[i] = m0 + m1 + m2;
        }
        __syncthreads();

        // pass B: vertical sums + select, rows/cols [1,39)
        for (int i = tid; i < 38 * 38; i += 256) {
            int q = i / 38;
            int ry = 1 + q, rx = 1 + (i - q * 38);
            int idx = ry * RD + rx;
            float n = sHM[idx - RD] + sHM[idx] + sHM[idx + RD];
            float y = sHX[idx - RD] + sHX[idx] + sHX[idx + RD];
            float c = cur[idx];
            unsigned long long row = br[ry + (HB - HD)];
            bool masked = ((row >> (rx + 3)) & 1ULL) != 0ULL;    // eb!=0 -> replace
            float avg = y * __builtin_amdgcn_rcpf(n);
            nxt[idx] = (masked && n > 0.5f) ? avg : c;
        }
        __syncthreads();

        // border blocks: edge-replicate the evolving image halo
        if (borderB) {
            for (int i = tid; i < RD * RD; i += 256) {
                int ry = i / RD, rx = i - ry * RD;
                int ryc = clampi(ry, topB ? HD : 0, botB ? (RD - 1 - HD) : RD - 1);
                int rxc = clampi(rx, leftB ? HD : 0, rightB ? (RD - 1 - HD) : RD - 1);
                if (ryc != ry || rxc != rx) nxt[i] = nxt[ryc * RD + rxc];
            }
        }
        __syncthreads();
        float* t = cur; cur = nxt; nxt = t;
    }

    // ---- store tile ----
    for (int i = tid; i < TILE * TILE; i += 256) {
        int ty = i >> 5, tx = i & 31;
        op[(size_t)(y0 + ty) * W_ + (x0 + tx)] = cur[(ty + HD) * RD + (tx + HD)];
    }
}

// ---------------- Stage 2: separable dilated 7-tap Gaussian ----------------
// H-pass reads taps straight from global (L1 catches the 7x overlap);
// only the H-pass result (width x (h+36)) lives in LDS.
#define GTW 64
#define GTH 64
#define GHALO 18
#define GRH (GTH + 2*GHALO)   // 100

__global__ __launch_bounds__(256)
void bsws_stage2(const float* __restrict__ ing, float* __restrict__ outg)
{
    __shared__ float sH[GRH][GTW];   // 100 x 64 x 4B = 25.6 KB

    const int tid = threadIdx.x;
    const int x0 = blockIdx.x * GTW;
    const int y0 = blockIdx.y * GTH;
    const size_t plane = (size_t)H_ * W_;
    const float* ip = ing  + blockIdx.z * plane;
    float*       op = outg + blockIdx.z * plane;

    const float W0 = 0.39905027965f;
    const float W1 = 0.24203622800f;
    const float W2 = 0.05400558260f;
    const float W3 = 0.00443304810f;

    // horizontal pass: 100 rows x 64 cols, taps at +-{0,6,12,18}, edge clamp
    for (int i = tid; i < GRH * GTW; i += 256) {
        int row = i >> 6, col = i & 63;
        int gy = clampi(y0 - GHALO + row, 0, H_ - 1);
        const float* rowp = ip + (size_t)gy * W_;
        int gx = x0 + col;
        float acc = W3 * (rowp[clampi(gx - 18, 0, W_ - 1)] + rowp[clampi(gx + 18, 0, W_ - 1)])
                  + W2 * (rowp[clampi(gx - 12, 0, W_ - 1)] + rowp[clampi(gx + 12, 0, W_ - 1)])
                  + W1 * (rowp[clampi(gx - 6,  0, W_ - 1)] + rowp[clampi(gx + 6,  0, W_ - 1)])
                  + W0 *  rowp[gx];
        sH[row][col] = acc;
    }
    __syncthreads();

    // vertical pass + coalesced store
    for (int i = tid; i < GTH * GTW; i += 256) {
        int ty = i >> 6, tx = i & 63;
        float acc = W3 * (sH[ty][tx]      + sH[ty + 36][tx])
                  + W2 * (sH[ty + 6][tx]  + sH[ty + 30][tx])
                  + W1 * (sH[ty + 12][tx] + sH[ty + 24][tx])
                  + W0 *  sH[ty + 18][tx];
        op[(size_t)(y0 + ty) * W_ + (x0 + tx)] = acc;
    }
}

extern "C" void kernel_launch(void* const* d_in, const int* in_sizes, int n_in,
                              void* d_out, int out_size, void* d_ws, size_t ws_size,
                              hipStream_t stream) {
    const float* x    = (const float*)d_in[0];
    const int*   pred = (const int*)d_in[1];
    float*       out  = (float*)d_out;
    float*       mid  = (float*)d_ws;   // 16.78 MB

    bsws_stage1<<<dim3(W_ / TILE, H_ / TILE, B_), dim3(256), 0, stream>>>(x, pred, mid);
    bsws_stage2<<<dim3(W_ / GTW, H_ / GTH, B_), dim3(256), 0, stream>>>(mid, out);
}

// Round 3
// 122.516 us; speedup vs baseline: 1.4304x; 1.4304x over previous
//
#include <hip/hip_runtime.h>

#define B_ 8
#define H_ 512
#define W_ 1024
#define NPX (B_*H_*W_)

// ---------------- Stage 1 geometry ----------------
#define TILE 32
#define HD 4                 // evolving-image halo (r_max=3 + 1 conv)
#define RD 40                // TILE + 2*HD
#define HB 7                 // boundary halo = HD + 3 (dist cap)
#define RB 46                // TILE + 2*HB
#define HP 8                 // pred halo = HB + 1
#define RP 48                // TILE + 2*HP

__device__ __forceinline__ int clampi(int v, int lo, int hi) {
    return v < lo ? lo : (v > hi ? hi : v);
}
__device__ __forceinline__ int imax(int a, int b) { return a > b ? a : b; }
__device__ __forceinline__ int imin(int a, int b) { return a < b ? a : b; }

// boundaries + (fast path: all-boundary => identity) + general masked-average path
__global__ __launch_bounds__(256)
void bsws_stage1(const float* __restrict__ xg, const int* __restrict__ predg,
                 float* __restrict__ outg)
{
    __shared__ int sPred[RP * RP];                    // 9.2 KB
    __shared__ unsigned long long sB[4][RB];          // b0..b3 row bitmaps
    __shared__ int sFlag;
    __shared__ float sA[RD * RD];                     // ping (general path)
    __shared__ float sC[RD * RD];                     // pong
    __shared__ float sHX[RD * RD];                    // horizontal masked-x sums
    __shared__ float sHM[RD * RD];                    // horizontal mask sums

    const int tid = threadIdx.x;
    const int x0 = blockIdx.x * TILE;
    const int y0 = blockIdx.y * TILE;
    const size_t plane = (size_t)H_ * W_;
    const int*   pp = predg + blockIdx.z * plane;
    const float* xp = xg    + blockIdx.z * plane;
    float*       op = outg  + blockIdx.z * plane;

    const bool leftB  = (x0 == 0), rightB = (x0 + TILE == W_);
    const bool topB   = (y0 == 0), botB   = (y0 + TILE == H_);
    const bool borderB = leftB || rightB || topB || botB;

    // ---- load pred region (sentinel -1 OOB); vectorized for interior blocks ----
    if (!borderB) {
        for (int i = tid; i < (RP * RP) / 4; i += 256) {     // 576 int4s
            int ry = i / (RP / 4);
            int c4 = i - ry * (RP / 4);
            int gy = y0 - HP + ry;
            int4 v = *(const int4*)(pp + (size_t)gy * W_ + (x0 - HP) + 4 * c4);
            *(int4*)&sPred[ry * RP + 4 * c4] = v;
        }
    } else {
        for (int i = tid; i < RP * RP; i += 256) {
            int ry = i / RP, rx = i - ry * RP;
            int gy = y0 - HP + ry, gx = x0 - HP + rx;
            sPred[i] = (gy >= 0 && gy < H_ && gx >= 0 && gx < W_) ? pp[(size_t)gy * W_ + gx] : -1;
        }
    }
    __syncthreads();

    // ---- b0: boundary bitmap via ballot (lane = column) ----
    {
        const int lane = tid & 63, wv = tid >> 6;
        for (int row = wv; row < RB; row += 4) {
            bool pred = false;
            if (lane < RB) {
                const int py = row + 1, px = lane + 1;     // 48-frame
                int c = sPred[py * RP + px];
                if (c >= 0) {
                    int up = sPred[(py - 1) * RP + px];
                    int dn = sPred[(py + 1) * RP + px];
                    int lf = sPred[py * RP + px - 1];
                    int rt = sPred[py * RP + px + 1];
                    int ul = sPred[(py - 1) * RP + px - 1];
                    int ur = sPred[(py - 1) * RP + px + 1];
                    int dl = sPred[(py + 1) * RP + px - 1];
                    int dr = sPred[(py + 1) * RP + px + 1];
                    int mx = imax(imax(up, dn), imax(lf, rt));
                    int Bv = 0x7fffffff;
                    int mn = imin(imin(imin(up < 0 ? Bv : up, dn < 0 ? Bv : dn),
                                       imin(lf < 0 ? Bv : lf, rt < 0 ? Bv : rt)),
                                  imin(imin(ul < 0 ? Bv : ul, ur < 0 ? Bv : ur),
                                       imin(dl < 0 ? Bv : dl, dr < 0 ? Bv : dr)));
                    pred = (mx > c) || (mn < c);
                }
            }
            unsigned long long bal = __ballot(pred);
            if (lane == 0) sB[0][row] = bal;
        }
    }
    __syncthreads();

    // ---- fast-path check: every in-image pixel in the RB region is a boundary ----
    if (tid < 64) {
        bool ok = true;
        if (tid < RB) {
            int gy = y0 - HB + tid;
            if (gy >= 0 && gy < H_) {
                int jlo = leftB ? HB : 0;
                int jhi = rightB ? (RB - 1 - HB) : (RB - 1);
                unsigned long long vmask = (((1ULL << (jhi - jlo + 1)) - 1ULL) << jlo);
                ok = ((sB[0][tid] & vmask) == vmask);
            }
        }
        unsigned long long all = __ballot(ok);
        if (tid == 0) sFlag = (all == ~0ULL) ? 1 : 0;
    }
    __syncthreads();

    if (sFlag) {
        // out = x on this tile: straight float4 copy
        int ty = tid >> 3, tx4 = (tid & 7) * 4;
        const float4 v = *(const float4*)(xp + (size_t)(y0 + ty) * W_ + (x0 + tx4));
        *(float4*)(op + (size_t)(y0 + ty) * W_ + (x0 + tx4)) = v;
        return;
    }

    // =================== general path ===================
    for (int i = tid; i < RD * RD; i += 256) {
        int ry = i / RD, rx = i - ry * RD;
        int gy = clampi(y0 - HD + ry, 0, H_ - 1);
        int gx = clampi(x0 - HD + rx, 0, W_ - 1);
        sA[i] = xp[(size_t)gy * W_ + gx];
    }

    // cross-dilations b1..b3
    #pragma unroll
    for (int lvl = 1; lvl < 4; ++lvl) {
        __syncthreads();
        if (tid < RB) {
            unsigned long long c = sB[lvl - 1][tid];
            unsigned long long u = (tid > 0)      ? sB[lvl - 1][tid - 1] : 0ULL;
            unsigned long long d = (tid < RB - 1) ? sB[lvl - 1][tid + 1] : 0ULL;
            sB[lvl][tid] = c | (c << 1) | (c >> 1) | u | d;
        }
    }
    __syncthreads();

    // border blocks: edge-replicate bitmap halo
    if (borderB) {
        const bool act = tid < 4 * RB;
        unsigned long long val = 0; int lvl = 0, row = 0;
        if (act) {
            lvl = tid / RB; row = tid - lvl * RB;
            int srcRow = clampi(row, topB ? HB : 0, botB ? (RB - 1 - HB) : RB - 1);
            val = sB[lvl][srcRow];
            if (leftB) {
                unsigned long long b = (val >> HB) & 1ULL;
                unsigned long long lo = (1ULL << HB) - 1;
                val = (val & ~lo) | (b ? lo : 0ULL);
            }
            if (rightB) {
                const int jb = RB - 1 - HB;
                unsigned long long b = (val >> jb) & 1ULL;
                unsigned long long keep = (1ULL << (jb + 1)) - 1;
                unsigned long long hi = (((1ULL << RB) - 1) & ~keep);
                val = (val & keep) | (b ? hi : 0ULL);
            }
        }
        __syncthreads();
        if (act) sB[lvl][row] = val;
    }
    __syncthreads();

    // 4 masked-average iterations, separable 3x3 sums
    float* cur = sA;
    float* nxt = sC;
    #pragma unroll
    for (int it = 0; it < 4; ++it) {
        const int r = 3 - it;
        const unsigned long long* br = sB[r];

        for (int i = tid; i < RD * RD; i += 256) {
            int ry = i / RD, rx = i - ry * RD;
            unsigned long long row = br[ry + (HB - HD)];
            int rxm = rx > 0 ? rx - 1 : 0;
            int rxp = rx < RD - 1 ? rx + 1 : RD - 1;
            float m0 = ((row >> (rx + 2)) & 1ULL) ? 0.f : 1.f;
            float m1 = ((row >> (rx + 3)) & 1ULL) ? 0.f : 1.f;
            float m2 = ((row >> (rx + 4)) & 1ULL) ? 0.f : 1.f;
            float a0 = cur[ry * RD + rxm];
            float a1 = cur[ry * RD + rx];
            float a2 = cur[ry * RD + rxp];
            sHX[i] = m0 * a0 + m1 * a1 + m2 * a2;
            sHM[i] = m0 + m1 + m2;
        }
        __syncthreads();

        for (int i = tid; i < 38 * 38; i += 256) {
            int q = i / 38;
            int ry = 1 + q, rx = 1 + (i - q * 38);
            int idx = ry * RD + rx;
            float n = sHM[idx - RD] + sHM[idx] + sHM[idx + RD];
            float y = sHX[idx - RD] + sHX[idx] + sHX[idx + RD];
            float c = cur[idx];
            unsigned long long row = br[ry + (HB - HD)];
            bool masked = ((row >> (rx + 3)) & 1ULL) != 0ULL;
            float avg = y * __builtin_amdgcn_rcpf(n);
            nxt[idx] = (masked && n > 0.5f) ? avg : c;
        }
        __syncthreads();

        if (borderB) {
            for (int i = tid; i < RD * RD; i += 256) {
                int ry = i / RD, rx = i - ry * RD;
                int ryc = clampi(ry, topB ? HD : 0, botB ? (RD - 1 - HD) : RD - 1);
                int rxc = clampi(rx, leftB ? HD : 0, rightB ? (RD - 1 - HD) : RD - 1);
                if (ryc != ry || rxc != rx) nxt[i] = nxt[ryc * RD + rxc];
            }
        }
        __syncthreads();
        float* t = cur; cur = nxt; nxt = t;
    }

    for (int i = tid; i < TILE * TILE; i += 256) {
        int ty = i >> 5, tx = i & 31;
        op[(size_t)(y0 + ty) * W_ + (x0 + tx)] = cur[(ty + HD) * RD + (tx + HD)];
    }
}

// ---------------- Stage 2: separable dilated 7-tap Gaussian, flat 2-pass ----
#define GW0 0.39905027965f
#define GW1 0.24203622800f
#define GW2 0.05400558260f
#define GW3 0.00443304810f

__global__ __launch_bounds__(256)
void gaussH(const float* __restrict__ in, float* __restrict__ out)
{
    int idx = blockIdx.x * 256 + threadIdx.x;        // NPX threads
    const float* row = in + (idx & ~(W_ - 1));
    int gx = idx & (W_ - 1);
    float acc = GW3 * (row[clampi(gx - 18, 0, W_ - 1)] + row[clampi(gx + 18, 0, W_ - 1)])
              + GW2 * (row[clampi(gx - 12, 0, W_ - 1)] + row[clampi(gx + 12, 0, W_ - 1)])
              + GW1 * (row[clampi(gx - 6,  0, W_ - 1)] + row[clampi(gx + 6,  0, W_ - 1)])
              + GW0 *  row[gx];
    out[idx] = acc;
}

__global__ __launch_bounds__(256)
void gaussV(const float* __restrict__ in, float* __restrict__ out)
{
    int idx = blockIdx.x * 256 + threadIdx.x;
    int gx = idx & (W_ - 1);
    int gy = (idx >> 10) & (H_ - 1);
    const float* pl = in + (size_t)(idx >> 19 << 19);
    float acc = GW3 * (pl[(clampi(gy - 18, 0, H_ - 1) << 10) | gx] + pl[(clampi(gy + 18, 0, H_ - 1) << 10) | gx])
              + GW2 * (pl[(clampi(gy - 12, 0, H_ - 1) << 10) | gx] + pl[(clampi(gy + 12, 0, H_ - 1) << 10) | gx])
              + GW1 * (pl[(clampi(gy - 6,  0, H_ - 1) << 10) | gx] + pl[(clampi(gy + 6,  0, H_ - 1) << 10) | gx])
              + GW0 *  pl[(gy << 10) | gx];
    out[idx] = acc;
}

// fallback tiled stage2 (only if ws can't hold two planes)
#define GTW 64
#define GTH 64
#define GHALO 18
#define GRH (GTH + 2*GHALO)   // 100

__global__ __launch_bounds__(256)
void bsws_stage2_tiled(const float* __restrict__ ing, float* __restrict__ outg)
{
    __shared__ float sH[GRH][GTW];

    const int tid = threadIdx.x;
    const int x0 = blockIdx.x * GTW;
    const int y0 = blockIdx.y * GTH;
    const size_t plane = (size_t)H_ * W_;
    const float* ip = ing  + blockIdx.z * plane;
    float*       op = outg + blockIdx.z * plane;

    for (int i = tid; i < GRH * GTW; i += 256) {
        int row = i >> 6, col = i & 63;
        int gy = clampi(y0 - GHALO + row, 0, H_ - 1);
        const float* rowp = ip + (size_t)gy * W_;
        int gx = x0 + col;
        float acc = GW3 * (rowp[clampi(gx - 18, 0, W_ - 1)] + rowp[clampi(gx + 18, 0, W_ - 1)])
                  + GW2 * (rowp[clampi(gx - 12, 0, W_ - 1)] + rowp[clampi(gx + 12, 0, W_ - 1)])
                  + GW1 * (rowp[clampi(gx - 6,  0, W_ - 1)] + rowp[clampi(gx + 6,  0, W_ - 1)])
                  + GW0 *  rowp[gx];
        sH[row][col] = acc;
    }
    __syncthreads();

    for (int i = tid; i < GTH * GTW; i += 256) {
        int ty = i >> 6, tx = i & 63;
        float acc = GW3 * (sH[ty][tx]      + sH[ty + 36][tx])
                  + GW2 * (sH[ty + 6][tx]  + sH[ty + 30][tx])
                  + GW1 * (sH[ty + 12][tx] + sH[ty + 24][tx])
                  + GW0 *  sH[ty + 18][tx];
        op[(size_t)(y0 + ty) * W_ + (x0 + tx)] = acc;
    }
}

extern "C" void kernel_launch(void* const* d_in, const int* in_sizes, int n_in,
                              void* d_out, int out_size, void* d_ws, size_t ws_size,
                              hipStream_t stream) {
    const float* x    = (const float*)d_in[0];
    const int*   pred = (const int*)d_in[1];
    float*       out  = (float*)d_out;
    float*       mid  = (float*)d_ws;

    bsws_stage1<<<dim3(W_ / TILE, H_ / TILE, B_), dim3(256), 0, stream>>>(x, pred, mid);

    const size_t plane_bytes = (size_t)NPX * 4;
    if (ws_size >= 2 * plane_bytes) {
        float* midH = mid + NPX;
        gaussH<<<NPX / 256, 256, 0, stream>>>(mid, midH);
        gaussV<<<NPX / 256, 256, 0, stream>>>(midH, out);
    } else {
        bsws_stage2_tiled<<<dim3(W_ / GTW, H_ / GTH, B_), dim3(256), 0, stream>>>(mid, out);
    }
}